// Round 3
// baseline (105.749 us; speedup 1.0000x reference)
//
#include <hip/hip_runtime.h>

#define B_ 8
#define S_ 4096
#define D_ 64

// ---------------------------------------------------------------------------
// Kernel 1: per (batch, seq-chunk) block computes a partial M = K_r^T V_r
// (64x64) over its chunk, RoPE on the fly. Preferred config: 32-row chunks
// -> 1024 blocks (4/CU, 4 waves/SIMD), ONE stage: one vmem epoch, one
// barrier. General path pipelines stages (prefetch next under compute).
// ---------------------------------------------------------------------------
__global__ __launch_bounds__(256, 4) void rope_ktv_partials(
    const float* __restrict__ K, const float* __restrict__ V,
    const float* __restrict__ FK, const float* __restrict__ FV,
    float* __restrict__ part, int nchunk, int rowsPerChunk)
{
    __shared__ float kbuf[32][64];
    __shared__ float vbuf[32][64];
    const int t  = threadIdx.x;
    const int b  = blockIdx.x / nchunk;
    const int sBase = (blockIdx.x - b * nchunk) * rowsPerChunk;

    const int sl = t >> 4;          // staging row 0..15 (and +16)
    const int e0 = (t & 15) << 2;   // elem 0,4,...,60
    const int i0 = (t >> 4) << 2;   // acc tile row base (k index)
    const int j0 = (t & 15) << 2;   // acc tile col base (v index)

    const float* kb = K + (size_t)b * S_ * D_;
    const float* vb = V + (size_t)b * S_ * D_;

    float acc[4][4];
    #pragma unroll
    for (int a = 0; a < 4; ++a)
        #pragma unroll
        for (int c = 0; c < 4; ++c) acc[a][c] = 0.f;

    const int nStages = rowsPerChunk >> 5;   // 32 rows per stage

    // prefetch stage 0 (2 rows per thread, 8 independent float4 loads)
    int s = sBase + sl;
    float4 kA = *(const float4*)(kb + (size_t)s * D_ + e0);
    float4 vA = *(const float4*)(vb + (size_t)s * D_ + e0);
    float4 fA = *(const float4*)(FK + (size_t)s * D_ + e0);
    float4 gA = *(const float4*)(FV + (size_t)s * D_ + e0);
    float4 kB = *(const float4*)(kb + (size_t)(s + 16) * D_ + e0);
    float4 vB = *(const float4*)(vb + (size_t)(s + 16) * D_ + e0);
    float4 fB = *(const float4*)(FK + (size_t)(s + 16) * D_ + e0);
    float4 gB = *(const float4*)(FV + (size_t)(s + 16) * D_ + e0);

    for (int it = 0; it < nStages; ++it) {
        float4 kr, vr, kr2, vr2;
        kr.x  = kA.x*fA.x - kA.y*fA.y;  kr.y  = kA.x*fA.y + kA.y*fA.x;
        kr.z  = kA.z*fA.z - kA.w*fA.w;  kr.w  = kA.z*fA.w + kA.w*fA.z;
        vr.x  = vA.x*gA.x - vA.y*gA.y;  vr.y  = vA.x*gA.y + vA.y*gA.x;
        vr.z  = vA.z*gA.z - vA.w*gA.w;  vr.w  = vA.z*gA.w + vA.w*gA.z;
        kr2.x = kB.x*fB.x - kB.y*fB.y;  kr2.y = kB.x*fB.y + kB.y*fB.x;
        kr2.z = kB.z*fB.z - kB.w*fB.w;  kr2.w = kB.z*fB.w + kB.w*fB.z;
        vr2.x = vB.x*gB.x - vB.y*gB.y;  vr2.y = vB.x*gB.y + vB.y*gB.x;
        vr2.z = vB.z*gB.z - vB.w*gB.w;  vr2.w = vB.z*gB.w + vB.w*gB.z;

        if (it > 0) __syncthreads();             // prev stage readers done
        *(float4*)&kbuf[sl][e0]      = kr;
        *(float4*)&vbuf[sl][e0]      = vr;
        *(float4*)&kbuf[sl + 16][e0] = kr2;
        *(float4*)&vbuf[sl + 16][e0] = vr2;
        __syncthreads();

        if (it + 1 < nStages) {                  // prefetch hides under r-loop
            s = sBase + ((it + 1) << 5) + sl;
            kA = *(const float4*)(kb + (size_t)s * D_ + e0);
            vA = *(const float4*)(vb + (size_t)s * D_ + e0);
            fA = *(const float4*)(FK + (size_t)s * D_ + e0);
            gA = *(const float4*)(FV + (size_t)s * D_ + e0);
            kB = *(const float4*)(kb + (size_t)(s + 16) * D_ + e0);
            vB = *(const float4*)(vb + (size_t)(s + 16) * D_ + e0);
            fB = *(const float4*)(FK + (size_t)(s + 16) * D_ + e0);
            gB = *(const float4*)(FV + (size_t)(s + 16) * D_ + e0);
        }

        #pragma unroll
        for (int r = 0; r < 32; ++r) {
            float4 ka = *(const float4*)&kbuf[r][i0];  // 4 addrs/wave
            float4 vv = *(const float4*)&vbuf[r][j0];  // 2-way alias = free
            acc[0][0] += ka.x*vv.x; acc[0][1] += ka.x*vv.y; acc[0][2] += ka.x*vv.z; acc[0][3] += ka.x*vv.w;
            acc[1][0] += ka.y*vv.x; acc[1][1] += ka.y*vv.y; acc[1][2] += ka.y*vv.z; acc[1][3] += ka.y*vv.w;
            acc[2][0] += ka.z*vv.x; acc[2][1] += ka.z*vv.y; acc[2][2] += ka.z*vv.z; acc[2][3] += ka.z*vv.w;
            acc[3][0] += ka.w*vv.x; acc[3][1] += ka.w*vv.y; acc[3][2] += ka.w*vv.z; acc[3][3] += ka.w*vv.w;
        }
    }

    float* p = part + (size_t)blockIdx.x * (D_ * D_);
    #pragma unroll
    for (int a = 0; a < 4; ++a)
        *(float4*)(p + (size_t)(i0 + a) * D_ + j0) =
            make_float4(acc[a][0], acc[a][1], acc[a][2], acc[a][3]);
}

// ---------------------------------------------------------------------------
// Kernel 1.5: reduce partials -> M[8][64*64], folding in the 1/sqrt(D) scale.
// One thread per (b, cell); 4 independent accumulator streams, unroll 8
// -> up to 32 loads in flight, coalesced across threads.
// ---------------------------------------------------------------------------
__global__ __launch_bounds__(256) void reduce_partials(
    const float* __restrict__ part, float* __restrict__ M, int nchunk)
{
    const int g    = blockIdx.x * 256 + threadIdx.x;   // 0..32767
    const int b    = g >> 12;
    const int cell = g & 4095;
    const float* p = part + ((size_t)b * nchunk) * (D_ * D_) + cell;
    float s0 = 0.f, s1 = 0.f, s2 = 0.f, s3 = 0.f;
    int i = 0;
    #pragma unroll 8
    for (; i + 4 <= nchunk; i += 4) {
        s0 += p[(size_t)(i + 0) * (D_ * D_)];
        s1 += p[(size_t)(i + 1) * (D_ * D_)];
        s2 += p[(size_t)(i + 2) * (D_ * D_)];
        s3 += p[(size_t)(i + 3) * (D_ * D_)];
    }
    for (; i < nchunk; ++i) s0 += p[(size_t)i * (D_ * D_)];
    M[g] = 0.125f * ((s0 + s1) + (s2 + s3));   // 1/sqrt(64) folded here
}

// ---------------------------------------------------------------------------
// Kernel 2: per (batch, 32-row block): load pre-scaled M (16KB, 4 parallel
// float4/thr) into Mt[j][i] (stride-65 -> conflict-free column reads),
// RoPE+stage 32 q rows, each thread computes 8 rows x 1 col.
// ---------------------------------------------------------------------------
__global__ __launch_bounds__(256) void rope_q_matmul(
    const float* __restrict__ Q, const float* __restrict__ FQ,
    const float* __restrict__ M, float* __restrict__ OUT, int nb2)
{
    __shared__ float Mt[64][65];
    __shared__ float qbuf[32][64];
    const int t = threadIdx.x;
    const int b = blockIdx.x / nb2;
    const int rowBase = (blockIdx.x - b * nb2) * 32;

    const int sl = t >> 4;
    const int e0 = (t & 15) << 2;
    const float* qb = Q + (size_t)b * S_ * D_;

    const int r1 = rowBase + sl;
    float4 qA = *(const float4*)(qb + (size_t)r1 * D_ + e0);
    float4 fA = *(const float4*)(FQ + (size_t)r1 * D_ + e0);
    float4 qB = *(const float4*)(qb + (size_t)(r1 + 16) * D_ + e0);
    float4 fB = *(const float4*)(FQ + (size_t)(r1 + 16) * D_ + e0);

    const float* mb = M + (size_t)b * (D_ * D_);
    float4 m0 = *(const float4*)(mb + (t << 2));
    float4 m1 = *(const float4*)(mb + 1024 + (t << 2));
    float4 m2 = *(const float4*)(mb + 2048 + (t << 2));
    float4 m3 = *(const float4*)(mb + 3072 + (t << 2));

    float4 qr, qr2;
    qr.x  = qA.x*fA.x - qA.y*fA.y;  qr.y  = qA.x*fA.y + qA.y*fA.x;
    qr.z  = qA.z*fA.z - qA.w*fA.w;  qr.w  = qA.z*fA.w + qA.w*fA.z;
    qr2.x = qB.x*fB.x - qB.y*fB.y;  qr2.y = qB.x*fB.y + qB.y*fB.x;
    qr2.z = qB.z*fB.z - qB.w*fB.w;  qr2.w = qB.z*fB.w + qB.w*fB.z;
    *(float4*)&qbuf[sl][e0]      = qr;
    *(float4*)&qbuf[sl + 16][e0] = qr2;

    {   // scatter M transposed: cell = c*1024 + t*4 + d ; Mt[cell&63][cell>>6]
        const int c0 = (t << 2);
        const float mv[16] = { m0.x, m0.y, m0.z, m0.w,  m1.x, m1.y, m1.z, m1.w,
                               m2.x, m2.y, m2.z, m2.w,  m3.x, m3.y, m3.z, m3.w };
        #pragma unroll
        for (int c = 0; c < 4; ++c)
            #pragma unroll
            for (int d = 0; d < 4; ++d) {
                const int cell = c * 1024 + c0 + d;
                Mt[cell & 63][cell >> 6] = mv[c * 4 + d];
            }
    }
    __syncthreads();

    const int j  = t & 63;            // output column (lane)
    const int rg = (t >> 6) << 3;     // wave-uniform row group: 0,8,16,24
    float a[8];
    #pragma unroll
    for (int r = 0; r < 8; ++r) a[r] = 0.f;

    #pragma unroll
    for (int i = 0; i < 64; i += 4) {
        const float w0 = Mt[j][i], w1 = Mt[j][i+1], w2 = Mt[j][i+2], w3 = Mt[j][i+3];
        #pragma unroll
        for (int r = 0; r < 8; ++r) {
            float4 q = *(const float4*)&qbuf[rg + r][i];   // broadcast
            a[r] += q.x*w0 + q.y*w1 + q.z*w2 + q.w*w3;
        }
    }

    float* ob = OUT + ((size_t)b * S_ + rowBase + rg) * D_ + j;
    #pragma unroll
    for (int r = 0; r < 8; ++r)
        ob[(size_t)r * D_] = a[r];    // scale already folded into M
}

extern "C" void kernel_launch(void* const* d_in, const int* in_sizes, int n_in,
                              void* d_out, int out_size, void* d_ws, size_t ws_size,
                              hipStream_t stream)
{
    const float* Q  = (const float*)d_in[0];
    const float* K  = (const float*)d_in[1];
    const float* V  = (const float*)d_in[2];
    const float* FQ = (const float*)d_in[3];
    const float* FK = (const float*)d_in[4];
    const float* FV = (const float*)d_in[5];
    float* OUT = (float*)d_out;

    float* M    = (float*)d_ws;                       // 8*4096 floats = 128 KB
    float* part = (float*)d_ws + (size_t)B_ * D_ * D_;

    // Prefer 128 chunks/batch (1024 blocks, single-stage); shrink to fit ws.
    int nchunk = 128;
    while (nchunk > 1 &&
           (size_t)(B_ * D_ * D_ + B_ * nchunk * D_ * D_) * sizeof(float) > ws_size)
        nchunk >>= 1;
    const int rowsPerChunk = S_ / nchunk;

    rope_ktv_partials<<<dim3(B_ * nchunk), dim3(256), 0, stream>>>(
        K, V, FK, FV, part, nchunk, rowsPerChunk);

    reduce_partials<<<dim3((B_ * D_ * D_) / 256), dim3(256), 0, stream>>>(
        part, M, nchunk);

    const int nb2 = S_ / 32;   // 128 row-blocks per batch -> 1024 blocks
    rope_q_matmul<<<dim3(B_ * nb2), dim3(256), 0, stream>>>(
        Q, FQ, M, OUT, nb2);
}